// Round 2
// baseline (157.684 us; speedup 1.0000x reference)
//
#include <hip/hip_runtime.h>

// PCEN: M_t = (1-s) M_{t-1} + s x_t (M_{-1}=0);  y = (x/(eps+M)^alpha + 2)^0.5 - 2^0.5
// [B=64, C=128, T=4000] f32. 8192 independent rows.
// Strategy: one thread per (row, chunk-of-200), 256-step warmup approximates the
// EMA carry-in (error <= 0.975^256 ~ 1.5e-3, threshold is 9.7e-2). Chunk 0 is exact.
// Lanes = consecutive rows -> 64 sequential streams per wave, float4 loads/stores.
// Transcendentals: __builtin_amdgcn_logf = v_log_f32 (log2), __builtin_amdgcn_exp2f
// = v_exp_f32 (2^x) -- x^(-0.98) = exp2(-0.98*log2(x)), single HW instr each.

#define T_LEN   4000
#define NROWS   (64 * 128)        // 8192
#define CHUNK   200               // multiple of 4
#define WARM    256               // multiple of 4
#define NCHUNK  (T_LEN / CHUNK)   // 20

__device__ __forceinline__ float pcen_y(float x, float M) {
    const float NALPHA = -0.98f;
    const float EPS    = 1e-6f;
    const float SQRT2  = 1.41421356237309515f;  // delta^r, delta=2, r=0.5
    float p = __builtin_amdgcn_exp2f(NALPHA * __builtin_amdgcn_logf(M + EPS));
    return sqrtf(fmaf(x, p, 2.0f)) - SQRT2;
}

__global__ __launch_bounds__(256) void pcen_kernel(const float* __restrict__ x,
                                                   float* __restrict__ y) {
    const int tid   = blockIdx.x * 256 + threadIdx.x;
    const int row   = tid & (NROWS - 1);   // consecutive lanes -> consecutive rows
    const int chunk = tid >> 13;           // tid / 8192

    const float* __restrict__ xr = x + (size_t)row * T_LEN;
    float* __restrict__ yr       = y + (size_t)row * T_LEN;

    const float S   = 0.025f;
    const float OMS = 1.0f - 0.025f;

    const int tw = chunk * CHUNK;            // write start
    int t0 = tw - WARM; if (t0 < 0) t0 = 0;  // warmup start (chunk 0: exact from M=0)
    const int t1 = tw + CHUNK;

    float M = 0.0f;

    // warmup: EMA only, no output
    #pragma unroll 2
    for (int t = t0; t < tw; t += 4) {
        const float4 v = *reinterpret_cast<const float4*>(xr + t);
        M = fmaf(S, v.x, OMS * M);
        M = fmaf(S, v.y, OMS * M);
        M = fmaf(S, v.z, OMS * M);
        M = fmaf(S, v.w, OMS * M);
    }

    // payload: EMA + y, float4 stores
    #pragma unroll 2
    for (int t = tw; t < t1; t += 4) {
        const float4 v = *reinterpret_cast<const float4*>(xr + t);
        float4 o;
        M = fmaf(S, v.x, OMS * M);  o.x = pcen_y(v.x, M);
        M = fmaf(S, v.y, OMS * M);  o.y = pcen_y(v.y, M);
        M = fmaf(S, v.z, OMS * M);  o.z = pcen_y(v.z, M);
        M = fmaf(S, v.w, OMS * M);  o.w = pcen_y(v.w, M);
        *reinterpret_cast<float4*>(yr + t) = o;
    }
}

extern "C" void kernel_launch(void* const* d_in, const int* in_sizes, int n_in,
                              void* d_out, int out_size, void* d_ws, size_t ws_size,
                              hipStream_t stream) {
    const float* x = (const float*)d_in[0];
    float* y       = (float*)d_out;

    const int total = NROWS * NCHUNK;       // 163840 threads
    const int block = 256;
    const int grid  = total / block;        // 640 blocks

    pcen_kernel<<<grid, block, 0, stream>>>(x, y);
}

// Round 3
// 75.579 us; speedup vs baseline: 2.0864x; 2.0864x over previous
//
#include <hip/hip_runtime.h>

// PCEN [B=64,C=128,T=4000] f32: M_t = 0.975 M_{t-1} + 0.025 x_t (M_{-1}=0);
//   y = sqrt(x * (M+eps)^-0.98 + 2) - sqrt(2)
// 8192 rows, chunk-parallel in T with >=256-step EMA warmup (err ~ 0.975^256 = 1.5e-3,
// threshold 9.7e-2; chunks 0,1 warm exactly from t=0).
// R3: LDS-staged tiles so ALL global traffic is full-128B-line coalesced.
//   block = 128 threads = 128 consecutive rows, one chunk. Tile = 128 rows x 32 t.
//   load: 8 lanes x float4 = one full line per row; LDS stride 33 dwords ->
//   compute reads bank (row+j)%32 = 2-way (free). y overwrites x in LDS in place,
//   then coalesced float4 store of payload range.

#define T_LEN   4000
#define NROWS   8192
#define CHUNK   200
#define WARM    256
#define NCHUNK  20              // T_LEN / CHUNK
#define RPB     128             // rows per block (= block size)
#define NRG     (NROWS / RPB)   // 64 row groups
#define TT      32              // tile width in t (32 floats = 128B per row)
#define LSTRIDE 33              // padded row stride in LDS (dwords)

__global__ __launch_bounds__(RPB) void pcen_kernel(const float* __restrict__ x,
                                                   float* __restrict__ y) {
    __shared__ float tile[RPB * LSTRIDE];   // 16.5 KB

    const int tid    = threadIdx.x;
    const int rowgrp = blockIdx.x % NRG;
    const int chunk  = blockIdx.x / NRG;
    const int r0     = rowgrp * RPB;

    const int tw = chunk * CHUNK;           // payload start (mult of 8)
    const int te = tw + CHUNK;              // payload end   (mult of 8)
    int t0 = tw - WARM; if (t0 < 0) t0 = 0;
    t0 &= ~(TT - 1);                        // align warmup start to tile

    const float S   = 0.025f;
    const float OMS = 0.975f;

    const float* __restrict__ xg = x + (size_t)r0 * T_LEN;
    float*       __restrict__ yg = y + (size_t)r0 * T_LEN;

    float M = 0.0f;

    for (int tt = t0; tt < te; tt += TT) {
        const int jend = (te - tt < TT) ? (te - tt) : TT;   // 8..32, mult of 4

        // ---- coalesced load: seg s = k*RPB+tid; 8 consecutive lanes = 1 row's 128B
        #pragma unroll
        for (int k = 0; k < 8; ++k) {
            const int s   = k * RPB + tid;          // 0..1023
            const int row = s >> 3;
            const int f4  = s & 7;
            // tt is 32-aligned and tt+32 <= 4000 always (4000 = 125*32): full-tile
            // loads are in-bounds even when payload is partial.
            const float4 v = *reinterpret_cast<const float4*>(
                xg + (size_t)row * T_LEN + tt + f4 * 4);
            float* d = &tile[row * LSTRIDE + f4 * 4];
            d[0] = v.x; d[1] = v.y; d[2] = v.z; d[3] = v.w;
        }
        __syncthreads();

        // ---- recurrence on own row (row = tid), in-place y
        {
            float* rowp = &tile[tid * LSTRIDE];
            const int wend0 = (tw > tt) ? (tw - tt) : 0;    // warmup part of tile
            const int wend  = (wend0 < jend) ? wend0 : jend;
            int j = 0;
            for (; j < wend; ++j)
                M = fmaf(S, rowp[j], OMS * M);
            for (; j < jend; ++j) {
                const float v = rowp[j];
                M = fmaf(S, v, OMS * M);
                const float p = __builtin_amdgcn_exp2f(
                                    -0.98f * __builtin_amdgcn_logf(M + 1e-6f));
                rowp[j] = sqrtf(fmaf(v, p, 2.0f)) - 1.41421356237309515f;
            }
        }
        __syncthreads();

        // ---- coalesced store of payload float4 segs (tw, te are mult of 4)
        if (tt + jend > tw) {
            #pragma unroll
            for (int k = 0; k < 8; ++k) {
                const int s   = k * RPB + tid;
                const int row = s >> 3;
                const int f4  = s & 7;
                const int t   = tt + f4 * 4;
                if (t >= tw && t < te) {
                    const float* sp = &tile[row * LSTRIDE + f4 * 4];
                    float4 v;
                    v.x = sp[0]; v.y = sp[1]; v.z = sp[2]; v.w = sp[3];
                    *reinterpret_cast<float4*>(yg + (size_t)row * T_LEN + t) = v;
                }
            }
        }
        __syncthreads();   // tile is overwritten by next load
    }
}

extern "C" void kernel_launch(void* const* d_in, const int* in_sizes, int n_in,
                              void* d_out, int out_size, void* d_ws, size_t ws_size,
                              hipStream_t stream) {
    const float* x = (const float*)d_in[0];
    float* y       = (float*)d_out;
    const int grid = NRG * NCHUNK;   // 1280 blocks, 5/CU
    pcen_kernel<<<grid, RPB, 0, stream>>>(x, y);
}

// Round 4
// 52.735 us; speedup vs baseline: 2.9901x; 1.4332x over previous
//
#include <hip/hip_runtime.h>

// PCEN [B=64,C=128,T=4000] f32: M_t = 0.975 M_{t-1} + 0.025 x_t (M_{-1}=0);
//   y = sqrt(x * (M+1e-6)^-0.98 + 2) - sqrt(2)
// R4: wave-parallel affine scan -- EXACT, no warmup, no LDS.
//   One wave per row. Tile = 256 t (lane l owns t = base+4l..4l+3, float4 ->
//   fully coalesced 1KB/wave). EMA is linear: lane's 4-elem update is an affine
//   map M -> K*M + b with uniform K = 0.975^4. Geometric-weighted prefix sum of
//   b via 6-step Hillis-Steele (shfl_up + fma, constant K^d per step), then each
//   lane replays its 4 elements from its exact carry-in. Cross-tile carry M0 in
//   a register (decay 0.975^256 per tile). 8192 waves -> 2048 blocks x 256 =
//   8 blocks/CU = 32 waves/CU occupancy cap, zero LDS.

#define T_LEN 4000
#define TILE  256
#define NFULL (T_LEN / TILE)            // 15 full tiles
#define TAILL ((T_LEN - NFULL*TILE)/4)  // 40 active lanes in 160-elem tail

constexpr double dpow(double b, int e) { double r = 1.0; for (int i = 0; i < e; ++i) r *= b; return r; }

__device__ __forceinline__ float pcen_y(float x, float M) {
    float p = __builtin_amdgcn_exp2f(-0.98f * __builtin_amdgcn_logf(M + 1e-6f));
    return sqrtf(fmaf(x, p, 2.0f)) - 1.41421356237309515f;
}

__global__ __launch_bounds__(256) void pcen_kernel(const float* __restrict__ x,
                                                   float* __restrict__ y) {
    const int wid  = threadIdx.x >> 6;
    const int lane = threadIdx.x & 63;
    const int row  = blockIdx.x * 4 + wid;

    const float S = 0.025f, OMS = 0.975f;
    const float K1  = (float)dpow(0.975, 4);
    const float K2  = (float)dpow(0.975, 8);
    const float K4  = (float)dpow(0.975, 16);
    const float K8  = (float)dpow(0.975, 32);
    const float K16 = (float)dpow(0.975, 64);
    const float K32 = (float)dpow(0.975, 128);
    const float KT  = (float)dpow(0.975, 256);   // whole-tile decay

    // c = 0.975^(4*lane): decay across the lanes below this one
    const float c = __builtin_amdgcn_exp2f((float)lane * (4.0f * -0.036525699374528f));

    const float* __restrict__ xr = x + (size_t)row * T_LEN;
    float*       __restrict__ yr = y + (size_t)row * T_LEN;

    float M0 = 0.0f;
    float4 vn = *reinterpret_cast<const float4*>(xr + lane * 4);  // prefetch tile 0

    for (int t = 0; t < NFULL; ++t) {
        const float4 v = vn;
        if (t + 1 < NFULL)   // prefetch next tile (independent of scan)
            vn = *reinterpret_cast<const float4*>(xr + (t + 1) * TILE + lane * 4);

        // local affine offset: apply 4 steps from M=0
        float b = S * v.x;
        b = fmaf(S, v.y, OMS * b);
        b = fmaf(S, v.z, OMS * b);
        b = fmaf(S, v.w, OMS * b);

        // inclusive scan: Ssc_i = sum_{j<=i} K^(i-j) b_j,  K = 0.975^4
        float Ssc = b, tv;
        tv = __shfl_up(Ssc, 1);  Ssc = fmaf(K1,  (lane >= 1  ? tv : 0.0f), Ssc);
        tv = __shfl_up(Ssc, 2);  Ssc = fmaf(K2,  (lane >= 2  ? tv : 0.0f), Ssc);
        tv = __shfl_up(Ssc, 4);  Ssc = fmaf(K4,  (lane >= 4  ? tv : 0.0f), Ssc);
        tv = __shfl_up(Ssc, 8);  Ssc = fmaf(K8,  (lane >= 8  ? tv : 0.0f), Ssc);
        tv = __shfl_up(Ssc, 16); Ssc = fmaf(K16, (lane >= 16 ? tv : 0.0f), Ssc);
        tv = __shfl_up(Ssc, 32); Ssc = fmaf(K32, (lane >= 32 ? tv : 0.0f), Ssc);

        // exclusive carry-in for this lane
        float Sex = __shfl_up(Ssc, 1); if (lane == 0) Sex = 0.0f;
        float M = fmaf(c, M0, Sex);

        float4 o;
        M = fmaf(S, v.x, OMS * M);  o.x = pcen_y(v.x, M);
        M = fmaf(S, v.y, OMS * M);  o.y = pcen_y(v.y, M);
        M = fmaf(S, v.z, OMS * M);  o.z = pcen_y(v.z, M);
        M = fmaf(S, v.w, OMS * M);  o.w = pcen_y(v.w, M);
        *reinterpret_cast<float4*>(yr + t * TILE + lane * 4) = o;

        // advance cross-tile carry
        const float S63 = __shfl(Ssc, 63);
        M0 = fmaf(KT, M0, S63);
    }

    // tail: 160 elements, lanes 0..39 active
    {
        const bool act = lane < TAILL;
        float4 v = make_float4(0.0f, 0.0f, 0.0f, 0.0f);
        if (act) v = *reinterpret_cast<const float4*>(xr + NFULL * TILE + lane * 4);

        float b = S * v.x;
        b = fmaf(S, v.y, OMS * b);
        b = fmaf(S, v.z, OMS * b);
        b = fmaf(S, v.w, OMS * b);

        float Ssc = b, tv;
        tv = __shfl_up(Ssc, 1);  Ssc = fmaf(K1,  (lane >= 1  ? tv : 0.0f), Ssc);
        tv = __shfl_up(Ssc, 2);  Ssc = fmaf(K2,  (lane >= 2  ? tv : 0.0f), Ssc);
        tv = __shfl_up(Ssc, 4);  Ssc = fmaf(K4,  (lane >= 4  ? tv : 0.0f), Ssc);
        tv = __shfl_up(Ssc, 8);  Ssc = fmaf(K8,  (lane >= 8  ? tv : 0.0f), Ssc);
        tv = __shfl_up(Ssc, 16); Ssc = fmaf(K16, (lane >= 16 ? tv : 0.0f), Ssc);
        tv = __shfl_up(Ssc, 32); Ssc = fmaf(K32, (lane >= 32 ? tv : 0.0f), Ssc);

        float Sex = __shfl_up(Ssc, 1); if (lane == 0) Sex = 0.0f;
        float M = fmaf(c, M0, Sex);

        float4 o;
        M = fmaf(S, v.x, OMS * M);  o.x = pcen_y(v.x, M);
        M = fmaf(S, v.y, OMS * M);  o.y = pcen_y(v.y, M);
        M = fmaf(S, v.z, OMS * M);  o.z = pcen_y(v.z, M);
        M = fmaf(S, v.w, OMS * M);  o.w = pcen_y(v.w, M);
        if (act)
            *reinterpret_cast<float4*>(yr + NFULL * TILE + lane * 4) = o;
    }
}

extern "C" void kernel_launch(void* const* d_in, const int* in_sizes, int n_in,
                              void* d_out, int out_size, void* d_ws, size_t ws_size,
                              hipStream_t stream) {
    const float* x = (const float*)d_in[0];
    float* y       = (float*)d_out;
    pcen_kernel<<<8192 / 4, 256, 0, stream>>>(x, y);  // 2048 blocks, 4 rows each
}